// Round 4
// baseline (277.806 us; speedup 1.0000x reference)
//
#include <hip/hip_runtime.h>

#define P  7
#define GS 7
#define D  21
#define HH 80
#define WW 80
#define CC (D * GS * GS)   // 1029

// fl32(1/7) = 0.14285714924335479736328125f, bit pattern 0x3E124925.
__device__ __forceinline__ float recip7() {
    union { unsigned u; float f; } c; c.u = 0x3E124925u; return c.f;
}

// a*b + c with a HARD barrier between mul and add so no fma contraction can
// occur regardless of -ffp-contract. Replicates "mul then add" in f32.
__device__ __forceinline__ float mul_add_nofma(float a, float b, float c) {
    float t = a * b;
    asm volatile("" : "+v"(t));   // opaque: compiler cannot fuse across this
    return t + c;
}

__global__ __launch_bounds__(256) void psroi_pool_kernel(
    const float* __restrict__ feat,   // (N, 1029, 80, 80)
    const float* __restrict__ rois,   // (R, 5)
    float* __restrict__ out,          // (R, 21, 7, 7)
    int total)
{
    int tid = blockIdx.x * blockDim.x + threadIdx.x;
    if (tid >= total) return;

    int pw   = tid % P;
    int ph   = (tid / P) % P;
    int ctop = (tid / (P * P)) % D;
    int r    = tid / (P * P * D);

    const float* roi = rois + (size_t)r * 5;
    int b = (int)roi[0];

    // ---- float32 edge arithmetic; division-by-7 as reciprocal MULTIPLY ----
    float x1 = rintf(roi[1]) * 0.0625f;            // exact dyadic
    float y1 = rintf(roi[2]) * 0.0625f;
    float x2 = (rintf(roi[3]) + 1.0f) * 0.0625f;   // exact dyadic
    float y2 = (rintf(roi[4]) + 1.0f) * 0.0625f;

    float qw = fmaxf(x2 - x1, 0.1f);               // exact
    float qh = fmaxf(y2 - y1, 0.1f);
    float bin_w = qw * recip7();                   // fl(q * fl(1/7)) — XLA-style
    float bin_h = qh * recip7();
    asm volatile("" : "+v"(bin_w), "+v"(bin_h));   // pin: no refolding into div/fma

    float hs_f = floorf(mul_add_nofma((float)ph,       bin_h, y1));
    float he_f = ceilf (mul_add_nofma((float)(ph + 1), bin_h, y1));
    float ws_f = floorf(mul_add_nofma((float)pw,       bin_w, x1));
    float we_f = ceilf (mul_add_nofma((float)(pw + 1), bin_w, x1));

    int hs = (int)fminf(fmaxf(hs_f, 0.0f), 80.0f);
    int he = (int)fminf(fmaxf(he_f, 0.0f), 80.0f);
    int ws = (int)fminf(fmaxf(ws_f, 0.0f), 80.0f);
    int we = (int)fminf(fmaxf(we_f, 0.0f), 80.0f);

    // gh = ph, gw = pw since GS == P == 7 (arange(P)*GS//P == arange(P))
    int c = (ctop * GS + ph) * GS + pw;
    const float* plane = feat + ((size_t)b * CC + c) * (HH * WW);

    float s = 0.0f;
    for (int h = hs; h < he; ++h) {
        const float* row = plane + h * WW;
        for (int w = ws; w < we; ++w) {
            s += row[w];
        }
    }

    int area = (he - hs) * (we - ws);
    out[tid] = (area > 0) ? (s / (float)area) : 0.0f;
}

extern "C" void kernel_launch(void* const* d_in, const int* in_sizes, int n_in,
                              void* d_out, int out_size, void* d_ws, size_t ws_size,
                              hipStream_t stream)
{
    const float* feat = (const float*)d_in[0];
    const float* rois = (const float*)d_in[1];
    float* out        = (float*)d_out;

    int R     = in_sizes[1] / 5;
    int total = R * D * P * P;   // == out_size

    int threads = 256;
    int blocks  = (total + threads - 1) / threads;
    psroi_pool_kernel<<<blocks, threads, 0, stream>>>(feat, rois, out, total);
}

// Round 5
// 72.806 us; speedup vs baseline: 3.8157x; 3.8157x over previous
//
#include <hip/hip_runtime.h>

#define P   7
#define GS  7
#define D   21
#define HH  80
#define WW  80
#define CC  (D * GS * GS)        // 1029
#define PLANE (HH * WW)          // 6400 floats

// fl32(1/7) = 0x3E124925 — the golden divides via reciprocal multiply.
__device__ __forceinline__ float recip7() {
    union { unsigned u; float f; } c; c.u = 0x3E124925u; return c.f;
}

// a*b + c with a HARD barrier between mul and add: no fma contraction ever.
__device__ __forceinline__ float mul_add_nofma(float a, float b, float c) {
    float t = a * b;
    asm volatile("" : "+v"(t));
    return t + c;
}

// One block per (b, c) plane. Loads the plane into LDS once (coalesced),
// then computes output column c for every ROI with batch index b.
template <bool USE_WS>
__global__ __launch_bounds__(256) void psroi_plane_kernel(
    const float* __restrict__ feat,   // (N, 1029, 80, 80)
    const float* __restrict__ rois,   // (R, 5)
    float* __restrict__ dst,          // USE_WS ? ws_T[1029][R] : out[R][1029]
    int R)
{
    __shared__ float pl[PLANE];

    int bid = blockIdx.x;
    int b   = bid / CC;
    int c   = bid % CC;               // c == ctop*49 + gh*7 + gw == output channel
    int rem = c % (GS * GS);
    int gh  = rem / GS;               // == ph  (since arange(P)*GS//P == arange(P))
    int gw  = rem % GS;               // == pw

    // ---- stage plane (b, c) into LDS, fully coalesced float4 ----
    const float4* src4 = (const float4*)(feat + ((size_t)b * CC + c) * PLANE);
    float4* pl4 = (float4*)pl;
    for (int i = threadIdx.x; i < PLANE / 4; i += 256) pl4[i] = src4[i];
    __syncthreads();

    // ---- each thread handles ROIs r = tid, tid+256, ... ----
    for (int r = threadIdx.x; r < R; r += 256) {
        const float* roi = rois + (size_t)r * 5;
        if ((int)roi[0] != b) continue;

        // float32 edge arithmetic, op-for-op identical to the golden
        float x1 = rintf(roi[1]) * 0.0625f;
        float y1 = rintf(roi[2]) * 0.0625f;
        float x2 = (rintf(roi[3]) + 1.0f) * 0.0625f;
        float y2 = (rintf(roi[4]) + 1.0f) * 0.0625f;

        float bin_w = fmaxf(x2 - x1, 0.1f) * recip7();
        float bin_h = fmaxf(y2 - y1, 0.1f) * recip7();
        asm volatile("" : "+v"(bin_w), "+v"(bin_h));

        float hs_f = floorf(mul_add_nofma((float)gh,       bin_h, y1));
        float he_f = ceilf (mul_add_nofma((float)(gh + 1), bin_h, y1));
        float ws_f = floorf(mul_add_nofma((float)gw,       bin_w, x1));
        float we_f = ceilf (mul_add_nofma((float)(gw + 1), bin_w, x1));

        int hs = (int)fminf(fmaxf(hs_f, 0.0f), 80.0f);
        int he = (int)fminf(fmaxf(he_f, 0.0f), 80.0f);
        int ws = (int)fminf(fmaxf(ws_f, 0.0f), 80.0f);
        int we = (int)fminf(fmaxf(we_f, 0.0f), 80.0f);

        float s = 0.0f;
        for (int h = hs; h < he; ++h) {
            const float* row = pl + h * WW;
            for (int w = ws; w < we; ++w) s += row[w];
        }
        int area = (he - hs) * (we - ws);
        float val = (area > 0) ? (s / (float)area) : 0.0f;

        if (USE_WS) dst[(size_t)c * R + r] = val;      // transposed, coalesced in r
        else        dst[(size_t)r * CC + c] = val;     // direct, scattered
    }
}

// ws_T[1029][R] -> out[R][1029], 32x32 LDS tiles, both sides coalesced.
__global__ __launch_bounds__(256) void transpose_kernel(
    const float* __restrict__ in,    // [C][R]
    float* __restrict__ out,         // [R][C]
    int R, int C)
{
    __shared__ float tile[32][33];
    int r0 = blockIdx.x * 32;
    int c0 = blockIdx.y * 32;
    int tx = threadIdx.x;            // 0..31
    int ty = threadIdx.y;            // 0..7

    #pragma unroll
    for (int k = 0; k < 32; k += 8) {
        int c = c0 + ty + k, r = r0 + tx;
        if (c < C && r < R) tile[ty + k][tx] = in[(size_t)c * R + r];
    }
    __syncthreads();
    #pragma unroll
    for (int k = 0; k < 32; k += 8) {
        int r = r0 + ty + k, c = c0 + tx;
        if (r < R && c < C) out[(size_t)r * C + c] = tile[tx][ty + k];
    }
}

extern "C" void kernel_launch(void* const* d_in, const int* in_sizes, int n_in,
                              void* d_out, int out_size, void* d_ws, size_t ws_size,
                              hipStream_t stream)
{
    const float* feat = (const float*)d_in[0];
    const float* rois = (const float*)d_in[1];
    float* out        = (float*)d_out;

    int R = in_sizes[1] / 5;
    int N = in_sizes[0] / (CC * PLANE);

    size_t ws_need = (size_t)CC * R * sizeof(float);
    dim3 blk1(256);
    dim3 grd1(N * CC);

    if (ws_size >= ws_need) {
        float* ws_T = (float*)d_ws;
        psroi_plane_kernel<true><<<grd1, blk1, 0, stream>>>(feat, rois, ws_T, R);
        dim3 blk2(32, 8);
        dim3 grd2((R + 31) / 32, (CC + 31) / 32);
        transpose_kernel<<<grd2, blk2, 0, stream>>>(ws_T, out, R, CC);
    } else {
        psroi_plane_kernel<false><<<grd1, blk1, 0, stream>>>(feat, rois, out, R);
    }
}

// Round 6
// 55.303 us; speedup vs baseline: 5.0233x; 1.3165x over previous
//
#include <hip/hip_runtime.h>

#define P   7
#define GS  7
#define D   21
#define HH  80
#define WW  80
#define CC  (D * GS * GS)        // 1029
#define PLANE (HH * WW)          // 6400 floats
#define IW  81                   // integral-image row stride (81x81)

// fl32(1/7) = 0x3E124925 — the golden divides via reciprocal multiply.
__device__ __forceinline__ float recip7() {
    union { unsigned u; float f; } c; c.u = 0x3E124925u; return c.f;
}

// a*b + c with a HARD barrier between mul and add: no fma contraction ever.
__device__ __forceinline__ float mul_add_nofma(float a, float b, float c) {
    float t = a * b;
    asm volatile("" : "+v"(t));
    return t + c;
}

// ---------------- kernel A: per-ROI edge tables (exact golden arithmetic) ---
__global__ __launch_bounds__(256) void edge_kernel(
    const float* __restrict__ rois, int R,
    unsigned char* __restrict__ bArr,
    unsigned short* __restrict__ hshe,
    unsigned short* __restrict__ wswe)
{
    int r = blockIdx.x * 256 + threadIdx.x;
    if (r >= R) return;
    const float* roi = rois + (size_t)r * 5;
    bArr[r] = (unsigned char)(int)roi[0];

    float x1 = rintf(roi[1]) * 0.0625f;
    float y1 = rintf(roi[2]) * 0.0625f;
    float x2 = (rintf(roi[3]) + 1.0f) * 0.0625f;
    float y2 = (rintf(roi[4]) + 1.0f) * 0.0625f;
    float bin_w = fmaxf(x2 - x1, 0.1f) * recip7();
    float bin_h = fmaxf(y2 - y1, 0.1f) * recip7();
    asm volatile("" : "+v"(bin_w), "+v"(bin_h));

    #pragma unroll
    for (int g = 0; g < 7; ++g) {
        float hs_f = floorf(mul_add_nofma((float)g,       bin_h, y1));
        float he_f = ceilf (mul_add_nofma((float)(g + 1), bin_h, y1));
        float ws_f = floorf(mul_add_nofma((float)g,       bin_w, x1));
        float we_f = ceilf (mul_add_nofma((float)(g + 1), bin_w, x1));
        int hs = (int)fminf(fmaxf(hs_f, 0.0f), 80.0f);
        int he = (int)fminf(fmaxf(he_f, 0.0f), 80.0f);
        int ws = (int)fminf(fmaxf(ws_f, 0.0f), 80.0f);
        int we = (int)fminf(fmaxf(we_f, 0.0f), 80.0f);
        hshe[r * 7 + g] = (unsigned short)(hs | (he << 8));
        wswe[r * 7 + g] = (unsigned short)(ws | (we << 8));
    }
}

// ---------------- kernel B: stable per-batch ROI lists (ballot compaction) --
__global__ __launch_bounds__(512) void compact_kernel(
    const unsigned char* __restrict__ bArr, int R,
    int* __restrict__ list, int* __restrict__ count)
{
    int wave = threadIdx.x >> 6;   // one wave per batch
    int lane = threadIdx.x & 63;
    int b = wave;
    int offset = 0;
    for (int r0 = 0; r0 < R; r0 += 64) {
        int r = r0 + lane;
        bool m = (r < R) && (bArr[r] == (unsigned char)b);
        unsigned long long mask = __ballot(m);
        int pos = offset + __popcll(mask & ((1ull << lane) - 1ull));
        if (m) list[b * R + pos] = r;
        offset += __popcll(mask);
    }
    if (lane == 0) count[b] = offset;
}

// ---------------- kernel C: per-plane LDS integral image + O(1) bins --------
template <bool FAST>
__global__ __launch_bounds__(256) void psroi_plane_kernel(
    const float* __restrict__ feat,
    const float* __restrict__ rois, int R,
    const unsigned short* __restrict__ hshe,
    const unsigned short* __restrict__ wswe,
    const int* __restrict__ list, const int* __restrict__ count,
    float* __restrict__ dst)     // FAST: ws_T[c][r]   else: out[r][c]
{
    __shared__ float ii[IW * IW];           // 81*81 floats = 25.6 KB

    int bid = blockIdx.x;
    int b   = bid / CC;
    int c   = bid % CC;
    int rem = c % (GS * GS);
    int gh  = rem / GS;
    int gw  = rem % GS;

    // stage plane into ii[1..80][1..80] (float4 global loads; 80%4==0 so each
    // float4 stays within one row)
    const float4* src4 = (const float4*)(feat + ((size_t)b * CC + c) * PLANE);
    for (int i = threadIdx.x; i < PLANE / 4; i += 256) {
        float4 v = src4[i];
        int idx = i * 4;
        int h = idx / WW, w = idx % WW;
        float* p = &ii[(h + 1) * IW + (w + 1)];
        p[0] = v.x; p[1] = v.y; p[2] = v.z; p[3] = v.w;
    }
    for (int i = threadIdx.x; i < IW; i += 256) {
        ii[i] = 0.0f;            // top row
        ii[i * IW] = 0.0f;       // left column
    }
    __syncthreads();

    // cumsum along H first (mirrors golden's axis=2-then-axis=3 association)
    if (threadIdx.x < WW) {
        int w = threadIdx.x + 1;
        float s = 0.0f;
        for (int h = 1; h <= HH; ++h) {
            s += ii[h * IW + w];
            ii[h * IW + w] = s;
        }
    }
    __syncthreads();
    // then cumsum along W
    if (threadIdx.x < HH) {
        int h = threadIdx.x + 1;
        float* row = &ii[h * IW];
        float s = 0.0f;
        for (int w = 1; w <= WW; ++w) {
            s += row[w];
            row[w] = s;
        }
    }
    __syncthreads();

    if (FAST) {
        int cnt = count[b];
        const int* lst = list + b * R;
        for (int i = threadIdx.x; i < cnt; i += 256) {
            int r  = lst[i];
            int hh = hshe[r * 7 + gh];
            int ww = wswe[r * 7 + gw];
            int hs = hh & 255, he = hh >> 8;
            int ws = ww & 255, we = ww >> 8;
            float s = ii[he * IW + we] - ii[hs * IW + we]
                    - ii[he * IW + ws] + ii[hs * IW + ws];
            int area = (he - hs) * (we - ws);
            dst[(size_t)c * R + r] = (area > 0) ? (s / (float)area) : 0.0f;
        }
    } else {
        // fallback: inline edges, scan all ROIs, scattered direct write
        for (int r = threadIdx.x; r < R; r += 256) {
            const float* roi = rois + (size_t)r * 5;
            if ((int)roi[0] != b) continue;
            float x1 = rintf(roi[1]) * 0.0625f;
            float y1 = rintf(roi[2]) * 0.0625f;
            float x2 = (rintf(roi[3]) + 1.0f) * 0.0625f;
            float y2 = (rintf(roi[4]) + 1.0f) * 0.0625f;
            float bin_w = fmaxf(x2 - x1, 0.1f) * recip7();
            float bin_h = fmaxf(y2 - y1, 0.1f) * recip7();
            asm volatile("" : "+v"(bin_w), "+v"(bin_h));
            float hs_f = floorf(mul_add_nofma((float)gh,       bin_h, y1));
            float he_f = ceilf (mul_add_nofma((float)(gh + 1), bin_h, y1));
            float ws_f = floorf(mul_add_nofma((float)gw,       bin_w, x1));
            float we_f = ceilf (mul_add_nofma((float)(gw + 1), bin_w, x1));
            int hs = (int)fminf(fmaxf(hs_f, 0.0f), 80.0f);
            int he = (int)fminf(fmaxf(he_f, 0.0f), 80.0f);
            int ws = (int)fminf(fmaxf(ws_f, 0.0f), 80.0f);
            int we = (int)fminf(fmaxf(we_f, 0.0f), 80.0f);
            float s = ii[he * IW + we] - ii[hs * IW + we]
                    - ii[he * IW + ws] + ii[hs * IW + ws];
            int area = (he - hs) * (we - ws);
            dst[(size_t)r * CC + c] = (area > 0) ? (s / (float)area) : 0.0f;
        }
    }
}

// ---------------- kernel D: ws_T[1029][R] -> out[R][1029] -------------------
__global__ __launch_bounds__(256) void transpose_kernel(
    const float* __restrict__ in, float* __restrict__ out, int R, int C)
{
    __shared__ float tile[32][33];
    int r0 = blockIdx.x * 32;
    int c0 = blockIdx.y * 32;
    int tx = threadIdx.x, ty = threadIdx.y;

    #pragma unroll
    for (int k = 0; k < 32; k += 8) {
        int c = c0 + ty + k, r = r0 + tx;
        if (c < C && r < R) tile[ty + k][tx] = in[(size_t)c * R + r];
    }
    __syncthreads();
    #pragma unroll
    for (int k = 0; k < 32; k += 8) {
        int r = r0 + ty + k, c = c0 + tx;
        if (r < R && c < C) out[(size_t)r * C + c] = tile[tx][ty + k];
    }
}

extern "C" void kernel_launch(void* const* d_in, const int* in_sizes, int n_in,
                              void* d_out, int out_size, void* d_ws, size_t ws_size,
                              hipStream_t stream)
{
    const float* feat = (const float*)d_in[0];
    const float* rois = (const float*)d_in[1];
    float* out        = (float*)d_out;

    int R = in_sizes[1] / 5;
    int N = in_sizes[0] / (CC * PLANE);

    // ws layout
    size_t off_wsT  = 0;
    size_t off_b    = off_wsT + (size_t)CC * R * sizeof(float);
    size_t off_hshe = off_b + (size_t)R;            // u8 array
    off_hshe = (off_hshe + 15) & ~(size_t)15;
    size_t off_wswe = off_hshe + (size_t)R * 7 * sizeof(unsigned short);
    size_t off_list = off_wswe + (size_t)R * 7 * sizeof(unsigned short);
    off_list = (off_list + 15) & ~(size_t)15;
    size_t off_cnt  = off_list + (size_t)N * R * sizeof(int);
    size_t need     = off_cnt + (size_t)N * sizeof(int);

    if (ws_size >= need && N <= 8) {
        char* ws = (char*)d_ws;
        float*          ws_T = (float*)(ws + off_wsT);
        unsigned char*  bArr = (unsigned char*)(ws + off_b);
        unsigned short* hshe = (unsigned short*)(ws + off_hshe);
        unsigned short* wswe = (unsigned short*)(ws + off_wswe);
        int*            list = (int*)(ws + off_list);
        int*            cnt  = (int*)(ws + off_cnt);

        edge_kernel<<<(R + 255) / 256, 256, 0, stream>>>(rois, R, bArr, hshe, wswe);
        compact_kernel<<<1, 64 * N, 0, stream>>>(bArr, R, list, cnt);
        psroi_plane_kernel<true><<<N * CC, 256, 0, stream>>>(
            feat, rois, R, hshe, wswe, list, cnt, ws_T);
        dim3 blk(32, 8), grd((R + 31) / 32, (CC + 31) / 32);
        transpose_kernel<<<grd, blk, 0, stream>>>(ws_T, out, R, CC);
    } else {
        psroi_plane_kernel<false><<<N * CC, 256, 0, stream>>>(
            feat, rois, R, nullptr, nullptr, nullptr, nullptr, out);
    }
}

// Round 7
// 52.473 us; speedup vs baseline: 5.2943x; 1.0539x over previous
//
#include <hip/hip_runtime.h>

#define P   7
#define GS  7
#define D   21
#define HH  80
#define WW  80
#define CC  (D * GS * GS)        // 1029
#define PLANE (HH * WW)          // 6400 floats
#define IW  81                   // integral-image row stride (odd => conflict-free cumsums)
#define NSEG 5
#define SEGLEN 16                // 80 / 5

// fl32(1/7) = 0x3E124925 — the golden divides via reciprocal multiply.
__device__ __forceinline__ float recip7() {
    union { unsigned u; float f; } c; c.u = 0x3E124925u; return c.f;
}

// a*b + c with a HARD barrier between mul and add: no fma contraction ever.
__device__ __forceinline__ float mul_add_nofma(float a, float b, float c) {
    float t = a * b;
    asm volatile("" : "+v"(t));
    return t + c;
}

// ---------- prep: edge tables + stable per-batch ROI lists, one block -------
__global__ __launch_bounds__(1024) void prep_kernel(
    const float* __restrict__ rois, int R, int N,
    unsigned short* __restrict__ hshe,
    unsigned short* __restrict__ wswe,
    int* __restrict__ list, int* __restrict__ count)
{
    __shared__ unsigned char bsh[2048];
    int tid = threadIdx.x;

    for (int r = tid; r < R; r += 1024) {
        const float* roi = rois + (size_t)r * 5;
        bsh[r] = (unsigned char)(int)roi[0];

        float x1 = rintf(roi[1]) * 0.0625f;
        float y1 = rintf(roi[2]) * 0.0625f;
        float x2 = (rintf(roi[3]) + 1.0f) * 0.0625f;
        float y2 = (rintf(roi[4]) + 1.0f) * 0.0625f;
        float bin_w = fmaxf(x2 - x1, 0.1f) * recip7();
        float bin_h = fmaxf(y2 - y1, 0.1f) * recip7();
        asm volatile("" : "+v"(bin_w), "+v"(bin_h));

        #pragma unroll
        for (int g = 0; g < 7; ++g) {
            float hs_f = floorf(mul_add_nofma((float)g,       bin_h, y1));
            float he_f = ceilf (mul_add_nofma((float)(g + 1), bin_h, y1));
            float ws_f = floorf(mul_add_nofma((float)g,       bin_w, x1));
            float we_f = ceilf (mul_add_nofma((float)(g + 1), bin_w, x1));
            int hs = (int)fminf(fmaxf(hs_f, 0.0f), 80.0f);
            int he = (int)fminf(fmaxf(he_f, 0.0f), 80.0f);
            int ws = (int)fminf(fmaxf(ws_f, 0.0f), 80.0f);
            int we = (int)fminf(fmaxf(we_f, 0.0f), 80.0f);
            hshe[r * 7 + g] = (unsigned short)(hs | (he << 8));
            wswe[r * 7 + g] = (unsigned short)(ws | (we << 8));
        }
    }
    __syncthreads();

    int wave = tid >> 6, lane = tid & 63;
    if (wave < N) {
        int b = wave, offset = 0;
        for (int r0 = 0; r0 < R; r0 += 64) {
            int r = r0 + lane;
            bool m = (r < R) && (bsh[r] == (unsigned char)b);
            unsigned long long mask = __ballot(m);
            int pos = offset + __popcll(mask & ((1ull << lane) - 1ull));
            if (m) list[b * R + pos] = r;
            offset += __popcll(mask);
        }
        if (lane == 0) count[b] = offset;
    }
}

// ---------- plane kernel: LDS integral image (2-level cumsum) + O(1) bins ---
template <bool FAST>
__global__ __launch_bounds__(512) void psroi_plane_kernel(
    const float* __restrict__ feat,
    const float* __restrict__ rois, int R,
    const unsigned short* __restrict__ hshe,
    const unsigned short* __restrict__ wswe,
    const int* __restrict__ list, const int* __restrict__ count,
    float* __restrict__ dst)     // FAST: ws_T[c][r]   else: out[r][c]
{
    __shared__ float ii[IW * IW];          // 26.2 KB
    __shared__ float tot[NSEG][HH];        // 1.6 KB

    int tid = threadIdx.x;
    int bid = blockIdx.x;
    int b   = bid / CC;
    int c   = bid % CC;
    int rem = c % (GS * GS);
    int gh  = rem / GS;
    int gw  = rem % GS;

    // ---- stage plane into ii[1..80][1..80] ----
    const float4* src4 = (const float4*)(feat + ((size_t)b * CC + c) * PLANE);
    for (int i = tid; i < PLANE / 4; i += 512) {
        float4 v = src4[i];
        int h = i / 20;            // (i*4)/80
        int w = (i % 20) * 4;      // (i*4)%80
        float* p = &ii[(h + 1) * IW + (w + 1)];
        p[0] = v.x; p[1] = v.y; p[2] = v.z; p[3] = v.w;
    }
    if (tid < IW) { ii[tid] = 0.0f; ii[tid * IW] = 0.0f; }
    __syncthreads();

    // ---- H cumsum (axis=2 first, as golden): 400 threads, regs per segment --
    bool act = tid < NSEG * WW;
    int seg = tid / WW;            // 0..4
    int lw  = tid % WW;            // 0..79
    float v[SEGLEN];
    {
        int col = lw + 1, h0 = seg * SEGLEN + 1;
        if (act) {
            float s = 0.0f;
            #pragma unroll
            for (int k = 0; k < SEGLEN; ++k) { v[k] = ii[(h0 + k) * IW + col]; s += v[k]; }
            tot[seg][lw] = s;
        }
        __syncthreads();
        if (act) {
            float off = 0.0f;
            #pragma unroll
            for (int j = 0; j < NSEG - 1; ++j) if (j < seg) off += tot[j][lw];
            float run = off;
            #pragma unroll
            for (int k = 0; k < SEGLEN; ++k) { run += v[k]; ii[(h0 + k) * IW + col] = run; }
        }
        __syncthreads();
    }
    // ---- W cumsum: same 400 threads, lw = row now ----
    {
        int row = lw + 1, w0 = seg * SEGLEN + 1;
        if (act) {
            float s = 0.0f;
            #pragma unroll
            for (int k = 0; k < SEGLEN; ++k) { v[k] = ii[row * IW + w0 + k]; s += v[k]; }
            tot[seg][lw] = s;
        }
        __syncthreads();
        if (act) {
            float off = 0.0f;
            #pragma unroll
            for (int j = 0; j < NSEG - 1; ++j) if (j < seg) off += tot[j][lw];
            float run = off;
            #pragma unroll
            for (int k = 0; k < SEGLEN; ++k) { run += v[k]; ii[row * IW + w0 + k] = run; }
        }
        __syncthreads();
    }

    if (FAST) {
        int cnt = count[b];
        const int* lst = list + b * R;
        for (int i = tid; i < cnt; i += 512) {
            int r  = lst[i];
            int hh = hshe[r * 7 + gh];
            int ww = wswe[r * 7 + gw];
            int hs = hh & 255, he = hh >> 8;
            int ws = ww & 255, we = ww >> 8;
            float s = ii[he * IW + we] - ii[hs * IW + we]
                    - ii[he * IW + ws] + ii[hs * IW + ws];
            int area = (he - hs) * (we - ws);
            dst[(size_t)c * R + r] = (area > 0) ? (s / (float)area) : 0.0f;
        }
    } else {
        for (int r = tid; r < R; r += 512) {
            const float* roi = rois + (size_t)r * 5;
            if ((int)roi[0] != b) continue;
            float x1 = rintf(roi[1]) * 0.0625f;
            float y1 = rintf(roi[2]) * 0.0625f;
            float x2 = (rintf(roi[3]) + 1.0f) * 0.0625f;
            float y2 = (rintf(roi[4]) + 1.0f) * 0.0625f;
            float bin_w = fmaxf(x2 - x1, 0.1f) * recip7();
            float bin_h = fmaxf(y2 - y1, 0.1f) * recip7();
            asm volatile("" : "+v"(bin_w), "+v"(bin_h));
            float hs_f = floorf(mul_add_nofma((float)gh,       bin_h, y1));
            float he_f = ceilf (mul_add_nofma((float)(gh + 1), bin_h, y1));
            float ws_f = floorf(mul_add_nofma((float)gw,       bin_w, x1));
            float we_f = ceilf (mul_add_nofma((float)(gw + 1), bin_w, x1));
            int hs = (int)fminf(fmaxf(hs_f, 0.0f), 80.0f);
            int he = (int)fminf(fmaxf(he_f, 0.0f), 80.0f);
            int ws = (int)fminf(fmaxf(ws_f, 0.0f), 80.0f);
            int we = (int)fminf(fmaxf(we_f, 0.0f), 80.0f);
            float s = ii[he * IW + we] - ii[hs * IW + we]
                    - ii[he * IW + ws] + ii[hs * IW + ws];
            int area = (he - hs) * (we - ws);
            dst[(size_t)r * CC + c] = (area > 0) ? (s / (float)area) : 0.0f;
        }
    }
}

// ---------- transpose: ws_T[1029][R] -> out[R][1029], 64x64 tiles -----------
__global__ __launch_bounds__(256) void transpose_kernel(
    const float* __restrict__ in, float* __restrict__ out, int R, int C)
{
    __shared__ float t[64][65];
    int r0 = blockIdx.x * 64;
    int c0 = blockIdx.y * 64;
    int tx = threadIdx.x;      // 0..63
    int ty = threadIdx.y;      // 0..3

    #pragma unroll
    for (int k0 = 0; k0 < 64; k0 += 4) {
        int k = k0 + ty;
        int cc = c0 + k, rr = r0 + tx;
        if (cc < C && rr < R) t[k][tx] = in[(size_t)cc * R + rr];
    }
    __syncthreads();
    #pragma unroll
    for (int k0 = 0; k0 < 64; k0 += 4) {
        int k = k0 + ty;
        int rr = r0 + k, cc = c0 + tx;
        if (rr < R && cc < C) out[(size_t)rr * C + cc] = t[tx][k];
    }
}

extern "C" void kernel_launch(void* const* d_in, const int* in_sizes, int n_in,
                              void* d_out, int out_size, void* d_ws, size_t ws_size,
                              hipStream_t stream)
{
    const float* feat = (const float*)d_in[0];
    const float* rois = (const float*)d_in[1];
    float* out        = (float*)d_out;

    int R = in_sizes[1] / 5;
    int N = in_sizes[0] / (CC * PLANE);

    size_t off_wsT  = 0;
    size_t off_hshe = (off_wsT + (size_t)CC * R * sizeof(float) + 15) & ~(size_t)15;
    size_t off_wswe = off_hshe + (size_t)R * 7 * sizeof(unsigned short);
    size_t off_list = (off_wswe + (size_t)R * 7 * sizeof(unsigned short) + 15) & ~(size_t)15;
    size_t off_cnt  = off_list + (size_t)N * R * sizeof(int);
    size_t need     = off_cnt + (size_t)N * sizeof(int);

    if (ws_size >= need && N <= 8 && R <= 2048) {
        char* ws = (char*)d_ws;
        float*          ws_T = (float*)(ws + off_wsT);
        unsigned short* hshe = (unsigned short*)(ws + off_hshe);
        unsigned short* wswe = (unsigned short*)(ws + off_wswe);
        int*            list = (int*)(ws + off_list);
        int*            cnt  = (int*)(ws + off_cnt);

        prep_kernel<<<1, 1024, 0, stream>>>(rois, R, N, hshe, wswe, list, cnt);
        psroi_plane_kernel<true><<<N * CC, 512, 0, stream>>>(
            feat, rois, R, hshe, wswe, list, cnt, ws_T);
        dim3 blk(64, 4), grd((R + 63) / 64, (CC + 63) / 64);
        transpose_kernel<<<grd, blk, 0, stream>>>(ws_T, out, R, CC);
    } else {
        psroi_plane_kernel<false><<<N * CC, 512, 0, stream>>>(
            feat, rois, R, nullptr, nullptr, nullptr, nullptr, out);
    }
}